// Round 1
// 468.950 us; speedup vs baseline: 1.0546x; 1.0546x over previous
//
#include <hip/hip_runtime.h>
#include <hip/hip_bf16.h>

typedef __hip_bfloat16 bf16;
typedef __bf16 bf16x8 __attribute__((ext_vector_type(8)));
typedef float f32x4 __attribute__((ext_vector_type(4)));

// async global->LDS, 16B per lane. LDS dest = wave-uniform base + lane*16.
__device__ __forceinline__ void async16(void* lds_base, const void* g) {
  __builtin_amdgcn_global_load_lds(
      (const __attribute__((address_space(1))) void*)g,
      (__attribute__((address_space(3))) void*)lds_base, 16, 0, 0);
}

// ---------------------------------------------------------------------------
// f32 -> bf16 flat convert (weights)
// ---------------------------------------------------------------------------
__global__ void cvt_bf16_kernel(const float* __restrict__ s, bf16* __restrict__ d, int n4) {
  const int i = blockIdx.x * 256 + threadIdx.x;
  if (i >= n4) return;
  const float4 v = ((const float4*)s)[i];
  bf16 h0 = __float2bfloat16(v.x), h1 = __float2bfloat16(v.y);
  bf16 h2 = __float2bfloat16(v.z), h3 = __float2bfloat16(v.w);
  ushort4 o;
  o.x = *(unsigned short*)&h0; o.y = *(unsigned short*)&h1;
  o.z = *(unsigned short*)&h2; o.w = *(unsigned short*)&h3;
  *(ushort4*)((unsigned short*)d + (size_t)i * 4) = o;
}

// ---------------------------------------------------------------------------
// x (B,L,H) fp32 -> xb (B,L,H) bf16  +  xbT (B,H,L) bf16 (for GLA V-frags)
// ---------------------------------------------------------------------------
__global__ __launch_bounds__(256) void convert_x_kernel(
    const float* __restrict__ x, bf16* __restrict__ xb, bf16* __restrict__ xbT) {
  __shared__ float tile[64][65];
  const int b = blockIdx.z;
  const int l0 = blockIdx.x * 64, d0 = blockIdx.y * 64;
  const int t = threadIdx.x;
  const int c = t & 63, r4 = t >> 6;
  const size_t base = ((size_t)b * 4096 + l0) * 2048 + d0;
#pragma unroll
  for (int i = 0; i < 16; ++i) {
    const int row = i * 4 + r4;
    const float v = x[base + (size_t)row * 2048 + c];
    tile[row][c] = v;
    xb[base + (size_t)row * 2048 + c] = __float2bfloat16(v);
  }
  __syncthreads();
  const size_t baseT = ((size_t)b * 2048 + d0) * 4096 + l0;
#pragma unroll
  for (int i = 0; i < 16; ++i) {
    const int dr = i * 4 + r4;
    xbT[baseT + (size_t)dr * 4096 + c] = __float2bfloat16(tile[c][dr]);
  }
}

// ---------------------------------------------------------------------------
// m97-style bf16 GEMM kept ONLY for the small logits GEMM (N=256).
// C[m,n] = sum_k A[m,k]*B[n,k]; 128x128 tile, BK=32, 256 thr, 16x16x32 MFMA.
// ---------------------------------------------------------------------------
template <int MODE>
__global__ __launch_bounds__(256, 2) void gemm_bt(
    const bf16* __restrict__ A0, const bf16* __restrict__ B0,
    const bf16* __restrict__ A1, const bf16* __restrict__ B1,
    float* __restrict__ outf, bf16* __restrict__ outb,
    const bf16* __restrict__ o_in, const float* __restrict__ rmsv,
    const float* __restrict__ gnw, int M, int N, int K) {
  __shared__ bf16 lA[128 * 32];
  __shared__ bf16 lB[128 * 32];
  const int tid = threadIdx.x;
  const int lane = tid & 63, wave = tid >> 6;
  const int l15 = lane & 15, l4 = lane >> 4;
  const int bm = blockIdx.x * 128, bn = blockIdx.y * 128;
  const int wm = (wave & 1) * 64, wn = (wave >> 1) * 64;
  const int srow = tid >> 2;
  const int skc = (tid & 3) * 8;

  const f32x4 fz = {0.f, 0.f, 0.f, 0.f};
  f32x4 acc[4][4];
#pragma unroll
  for (int i = 0; i < 4; ++i)
#pragma unroll
    for (int j = 0; j < 4; ++j) acc[i][j] = fz;

  bf16* lAu  = lA + wave * 512;
  bf16* lAu2 = lA + 2048 + wave * 512;
  bf16* lBu  = lB + wave * 512;
  bf16* lBu2 = lB + 2048 + wave * 512;

  const int npass = (MODE == 1) ? 2 : 1;
  for (int pass = 0; pass < npass; ++pass) {
    const bf16* Ap = (pass == 0) ? A0 : A1;
    const bf16* Bp = (pass == 0) ? B0 : B1;
    const bf16* gA0 = Ap + (size_t)(bm + srow) * K + skc;
    const bf16* gA1 = Ap + (size_t)(bm + srow + 64) * K + skc;
    const bf16* gB0 = Bp + (size_t)(bn + srow) * K + skc;
    const bf16* gB1 = Bp + (size_t)(bn + srow + 64) * K + skc;
    for (int k0 = 0; k0 < K; k0 += 32) {
      __syncthreads();
      async16(lAu, gA0 + k0);
      async16(lAu2, gA1 + k0);
      async16(lBu, gB0 + k0);
      async16(lBu2, gB1 + k0);
      __syncthreads();
      bf16x8 af[4], bfv[4];
#pragma unroll
      for (int mt = 0; mt < 4; ++mt)
        af[mt] = *(const bf16x8*)(lA + (wm + mt * 16 + l15) * 32 + l4 * 8);
#pragma unroll
      for (int nt = 0; nt < 4; ++nt)
        bfv[nt] = *(const bf16x8*)(lB + (wn + nt * 16 + l15) * 32 + l4 * 8);
#pragma unroll
      for (int mt = 0; mt < 4; ++mt)
#pragma unroll
        for (int nt = 0; nt < 4; ++nt)
          acc[mt][nt] = __builtin_amdgcn_mfma_f32_16x16x32_bf16(af[mt], bfv[nt], acc[mt][nt], 0, 0, 0);
    }
  }

#pragma unroll
  for (int mt = 0; mt < 4; ++mt)
#pragma unroll
    for (int r = 0; r < 4; ++r) {
      const int gr = bm + wm + mt * 16 + l4 * 4 + r;
#pragma unroll
      for (int nt = 0; nt < 4; ++nt) {
        const int gc = bn + wn + nt * 16 + l15;
        const float v = acc[mt][nt][r];
        if (MODE == 1) {
          const float o = (float)o_in[(size_t)gr * N + gc];
          const float on = o * rmsv[gr] * gnw[gc];
          const float sw = v / (1.f + __expf(-v));
          outb[(size_t)gr * N + gc] = __float2bfloat16(on * sw);
        } else {
          outf[(size_t)gr * N + gc] = v;
        }
      }
    }
}

// ---------------------------------------------------------------------------
// 256x256-tile 8-phase bf16 GEMM (T1 XCD-swizzle + T2 LDS XOR-swizzle +
// T3/T4 counted-vmcnt 8-phase pipeline + T5 setprio). K fixed = 2048/source.
// C[m,n] = sum_k A[m,k]*B[n,k]. MODE 1: dual-source (A0@B0 + A1@B1) with
// RMSNorm-gate-swish epilogue -> bf16. MODE 2: single source -> fp32.
// 512 threads = 8 waves (2M x 4N); per-wave output 128x64; BK=64.
// LDS 128 KiB: lA/lB[2 buf][2 half][128 rows][64 bf16], rows 128 B.
// Swizzle: 16B slot s' = s ^ (row&7), applied on the *global source* of
// global_load_lds (dest stays linear) and on the ds_read address.
// ---------------------------------------------------------------------------
#define QMFMA(AF, BF, MH, NH)                                               \
  do {                                                                      \
    __builtin_amdgcn_s_setprio(1);                                          \
    _Pragma("unroll") for (int ks_ = 0; ks_ < 2; ++ks_) {                   \
      _Pragma("unroll") for (int mt_ = 0; mt_ < 4; ++mt_) {                 \
        _Pragma("unroll") for (int nt_ = 0; nt_ < 2; ++nt_)                 \
            acc[(MH) * 4 + mt_][(NH) * 2 + nt_] =                           \
                __builtin_amdgcn_mfma_f32_16x16x32_bf16(                    \
                    AF[mt_][ks_], BF[nt_][ks_],                             \
                    acc[(MH) * 4 + mt_][(NH) * 2 + nt_], 0, 0, 0);          \
      }                                                                     \
    }                                                                       \
    __builtin_amdgcn_s_setprio(0);                                          \
  } while (0)

template <int MODE>
__global__ __launch_bounds__(512, 2) void gemm256(
    const bf16* __restrict__ A0, const bf16* __restrict__ B0,
    const bf16* __restrict__ A1, const bf16* __restrict__ B1,
    float* __restrict__ outf, bf16* __restrict__ outb,
    const bf16* __restrict__ o_in, const float* __restrict__ rmsv,
    const float* __restrict__ gnw, int M, int N) {
  __shared__ bf16 lA[2][16384];  // [buf][half*8192 + row*64 + col]
  __shared__ bf16 lB[2][16384];
  const int tid = threadIdx.x;
  const int lane = tid & 63;
  const int wave = tid >> 6;
  const int wmi = wave >> 2;   // 0..1  (M wave index)
  const int wni = wave & 3;    // 0..3  (N wave index)
  const int l15 = lane & 15, l4 = lane >> 4;
  const int axor = l15 & 7;    // row&7 for frag reads

  // T1: bijective XCD swizzle (grid % 8 == 0 here: 256 blocks)
  const int nwg = gridDim.x;
  const int cpx = nwg >> 3;
  int wg = blockIdx.x;
  wg = (wg & 7) * cpx + (wg >> 3);
  const int NBN = N >> 8;
  const int bm = (wg / NBN) * 256;
  const int bn = (wg % NBN) * 256;

  // staging geometry: chunk c = r*512 + tid -> (row = c>>3, slot = c&7);
  // global source pre-swizzled so linear LDS + XOR read = identity.
  const int srow = tid >> 3;                       // 0..63 (round 0)
  const int scol = ((tid & 7) ^ (srow & 7)) * 8;   // bf16 elems
  const size_t goff = (size_t)srow * 2048 + scol;  // K == 2048 always

  const int NT = (MODE == 1) ? 64 : 32;  // K-tiles of 64

  const bf16* Abase0 = A0 + (size_t)bm * 2048;
  const bf16* Abase1 = (MODE == 1) ? (A1 + (size_t)bm * 2048) : A0;
  const bf16* Bbase0 = B0 + (size_t)bn * 2048;
  const bf16* Bbase1 = (MODE == 1) ? (B1 + (size_t)bn * 2048) : B0;

  auto stageA = [&](int kt, int h, int buf) {
    int t = (kt < NT) ? kt : (NT - 1);  // tail: dummy re-stage (never read)
    const bf16* src = Abase0;
    int k0 = t * 64;
    if (MODE == 1 && t >= 32) { src = Abase1; k0 = (t - 32) * 64; }
    const bf16* g = src + (size_t)h * 128 * 2048 + k0 + goff;
    bf16* d = &lA[buf][h * 8192] + tid * 8;
    async16(d, g);
    async16(d + 4096, g + (size_t)64 * 2048);
  };
  auto stageB = [&](int kt, int h, int buf) {
    int t = (kt < NT) ? kt : (NT - 1);
    const bf16* src = Bbase0;
    int k0 = t * 64;
    if (MODE == 1 && t >= 32) { src = Bbase1; k0 = (t - 32) * 64; }
    const bf16* g = src + (size_t)h * 128 * 2048 + k0 + goff;
    bf16* d = &lB[buf][h * 8192] + tid * 8;
    async16(d, g);
    async16(d + 4096, g + (size_t)64 * 2048);
  };

  auto readA = [&](bf16x8 (&af)[4][2], int buf, int mh) {
    const bf16* base = &lA[buf][wmi * 8192];
#pragma unroll
    for (int mt = 0; mt < 4; ++mt)
#pragma unroll
      for (int ks = 0; ks < 2; ++ks)
        af[mt][ks] = *(const bf16x8*)(base + (mh * 64 + mt * 16 + l15) * 64 +
                                      (((ks * 4 + l4) ^ axor) << 3));
  };
  auto readB = [&](bf16x8 (&bb)[2][2], int buf, int nh) {
    const bf16* base = &lB[buf][(wni >> 1) * 8192];
#pragma unroll
    for (int nt = 0; nt < 2; ++nt)
#pragma unroll
      for (int ks = 0; ks < 2; ++ks)
        bb[nt][ks] = *(const bf16x8*)(base +
                                      ((wni & 1) * 64 + nh * 32 + nt * 16 + l15) * 64 +
                                      (((ks * 4 + l4) ^ axor) << 3));
  };

  const f32x4 fz = {0.f, 0.f, 0.f, 0.f};
  f32x4 acc[8][4];
#pragma unroll
  for (int i = 0; i < 8; ++i)
#pragma unroll
    for (int j = 0; j < 4; ++j) acc[i][j] = fz;

  // ---- prologue: tile0 (B then A), tile1 B. vmcnt(4) -> tile0 resident.
  stageB(0, 0, 0); stageB(0, 1, 0);
  stageA(0, 0, 0); stageA(0, 1, 0);
  stageB(1, 0, 1); stageB(1, 1, 1);
  asm volatile("s_waitcnt vmcnt(4)" ::: "memory");
  __builtin_amdgcn_s_barrier();

  bf16x8 aF[4][2], b0F[2][2], b1F[2][2];

  for (int kt = 0; kt < NT; ++kt) {
    const int cur = kt & 1, nxt = cur ^ 1;
    // -- phase 1: quadrant (0,0); stage (kt+1).A-h0 -> idle buf
    readA(aF, cur, 0);
    readB(b0F, cur, 0);
    stageA(kt + 1, 0, nxt);
    __builtin_amdgcn_s_barrier();
    asm volatile("s_waitcnt lgkmcnt(0)" ::: "memory");
    QMFMA(aF, b0F, 0, 0);
    __builtin_amdgcn_s_barrier();
    // -- phase 2: quadrant (0,1); stage (kt+1).A-h1
    readB(b1F, cur, 1);
    stageA(kt + 1, 1, nxt);
    __builtin_amdgcn_s_barrier();
    asm volatile("s_waitcnt lgkmcnt(0)" ::: "memory");
    QMFMA(aF, b1F, 0, 1);
    __builtin_amdgcn_s_barrier();
    // -- phase 3: quadrant (1,0); stage (kt+2).B-h0 into cur (B fully read)
    readA(aF, cur, 1);
    stageB(kt + 2, 0, cur);
    __builtin_amdgcn_s_barrier();
    asm volatile("s_waitcnt lgkmcnt(0)" ::: "memory");
    QMFMA(aF, b0F, 1, 0);
    __builtin_amdgcn_s_barrier();
    // -- phase 4: quadrant (1,1); stage (kt+2).B-h1; counted vmcnt(4):
    //    drains through (kt+1).A-h1, leaves (kt+2).B halves in flight.
    stageB(kt + 2, 1, cur);
    asm volatile("s_waitcnt vmcnt(4)" ::: "memory");
    __builtin_amdgcn_s_barrier();
    QMFMA(aF, b1F, 1, 1);
    __builtin_amdgcn_s_barrier();
    __builtin_amdgcn_sched_barrier(0);  // pin next-tile ds_reads below barrier
  }

  // ---- epilogue
#pragma unroll
  for (int i = 0; i < 8; ++i) {
#pragma unroll
    for (int r = 0; r < 4; ++r) {
      const int gr = bm + wmi * 128 + i * 16 + l4 * 4 + r;
#pragma unroll
      for (int j = 0; j < 4; ++j) {
        const int gc = bn + wni * 64 + j * 16 + l15;
        const float v = acc[i][j][r];
        if (MODE == 1) {
          const float o = (float)o_in[(size_t)gr * N + gc];
          const float on = o * rmsv[gr] * gnw[gc];
          const float sw = v / (1.f + __expf(-v));
          outb[(size_t)gr * N + gc] = __float2bfloat16(on * sw);
        } else {
          outf[(size_t)gr * N + gc] = v;
        }
      }
    }
  }
}

// ---------------------------------------------------------------------------
// per-row: q = softmax(logits[0:128]), k = sigmoid(logits[128:256]),
// gf = log_sigmoid(-k) = -log(1+exp(k)).  One wave per row.
// ---------------------------------------------------------------------------
__global__ __launch_bounds__(64) void qk_post_kernel(
    const float* __restrict__ logits, bf16* __restrict__ qb,
    bf16* __restrict__ kb, float* __restrict__ gfl) {
  const int row = blockIdx.x;
  const int t = threadIdx.x;
  const float* lr = logits + (size_t)row * 256;
  float a0 = lr[t], a1 = lr[t + 64];
  float m = fmaxf(a0, a1);
#pragma unroll
  for (int s = 32; s; s >>= 1) m = fmaxf(m, __shfl_xor(m, s));
  float e0 = __expf(a0 - m), e1 = __expf(a1 - m);
  float sum = e0 + e1;
#pragma unroll
  for (int s = 32; s; s >>= 1) sum += __shfl_xor(sum, s);
  const float inv = 1.f / sum;
  qb[(size_t)row * 128 + t]      = __float2bfloat16(e0 * inv);
  qb[(size_t)row * 128 + t + 64] = __float2bfloat16(e1 * inv);
  float b0 = lr[128 + t], b1 = lr[128 + t + 64];
  float k0 = 1.f / (1.f + __expf(-b0));
  float k1 = 1.f / (1.f + __expf(-b1));
  kb[(size_t)row * 128 + t]      = __float2bfloat16(k0);
  kb[(size_t)row * 128 + t + 64] = __float2bfloat16(k1);
  gfl[(size_t)row * 128 + t]      = -log1pf(__expf(k0));
  gfl[(size_t)row * 128 + t + 64] = -log1pf(__expf(k1));
}

// ---------------------------------------------------------------------------
// GLA sliding-window kernel. One block per (chunk, batch); 64 out rows.
// ---------------------------------------------------------------------------
__global__ __launch_bounds__(256, 2) void gla_kernel(
    const bf16* __restrict__ qb, const bf16* __restrict__ kb,
    const float* __restrict__ gfl, const bf16* __restrict__ xbT,
    bf16* __restrict__ ob, float* __restrict__ rmsv) {
  __shared__ bf16 sF1[64][136];   // q*e^{Bi-M}; later reused as masked A[i][jw]
  __shared__ bf16 sF2[128][136];  // rows 0..63 prev-chunk, 64..127 current
  __shared__ float sM[128];
  __shared__ float rowsq[64];
  const int tid = threadIdx.x;
  const int lane = tid & 63, wave = tid >> 6;
  const int l15 = lane & 15, l4 = lane >> 4;
  const int chunk = blockIdx.x, b = blockIdx.y;
  const int row0 = b * 4096 + chunk * 64;

  if (tid < 64) rowsq[tid] = 0.f;

  if (tid < 128) {
    float s = 0.f;
    for (int i = 0; i <= 32; ++i) s += gfl[(size_t)(row0 + i) * 128 + tid];
    sM[tid] = s;
  }
  __syncthreads();

  if (tid < 128) {
    const int d = tid;
    const float M = sM[d];
    float bi = 0.f;
    for (int i = 0; i < 64; ++i) {
      bi += gfl[(size_t)(row0 + i) * 128 + d];
      const float q = (float)qb[(size_t)(row0 + i) * 128 + d];
      const float k = (float)kb[(size_t)(row0 + i) * 128 + d];
      sF1[i][d]      = __float2bfloat16(q * __expf(bi - M));
      sF2[64 + i][d] = __float2bfloat16(k * __expf(M - bi));
    }
  } else {
    const int d = tid - 128;
    if (chunk == 0) {
      for (int j = 0; j < 64; ++j) sF2[j][d] = __float2bfloat16(0.f);
    } else {
      const float M = sM[d];
      float bw = 0.f;
      for (int j = 63; j >= 0; --j) {
        const float k = (float)kb[(size_t)(row0 - 64 + j) * 128 + d];
        sF2[j][d] = __float2bfloat16(k * __expf(M - bw));
        bw -= gfl[(size_t)(row0 - 64 + j) * 128 + d];
      }
    }
  }
  __syncthreads();

  const f32x4 fz = {0.f, 0.f, 0.f, 0.f};
  {
    f32x4 sacc[4][2];
#pragma unroll
    for (int mt = 0; mt < 4; ++mt) { sacc[mt][0] = fz; sacc[mt][1] = fz; }
    bf16x8 f1[4][4];
#pragma unroll
    for (int kt = 0; kt < 4; ++kt)
#pragma unroll
      for (int mt = 0; mt < 4; ++mt)
        f1[kt][mt] = *(const bf16x8*)(&sF1[mt * 16 + l15][kt * 32 + l4 * 8]);
#pragma unroll
    for (int nt = 0; nt < 2; ++nt)
#pragma unroll
      for (int kt = 0; kt < 4; ++kt) {
        const bf16x8 f2 = *(const bf16x8*)(&sF2[wave * 32 + nt * 16 + l15][kt * 32 + l4 * 8]);
#pragma unroll
        for (int mt = 0; mt < 4; ++mt)
          sacc[mt][nt] = __builtin_amdgcn_mfma_f32_16x16x32_bf16(f1[kt][mt], f2, sacc[mt][nt], 0, 0, 0);
      }
    __syncthreads();
#pragma unroll
    for (int mt = 0; mt < 4; ++mt)
#pragma unroll
      for (int nt = 0; nt < 2; ++nt)
#pragma unroll
        for (int r = 0; r < 4; ++r) {
          const int i = mt * 16 + l4 * 4 + r;
          const int jw = wave * 32 + nt * 16 + l15;
          const bool ok = (jw < 64) || (jw - 64 <= i);
          sF1[i][jw] = __float2bfloat16(ok ? sacc[mt][nt][r] : 0.f);
        }
    __syncthreads();
  }

  bf16x8 av[4][4];
#pragma unroll
  for (int kt = 0; kt < 4; ++kt)
#pragma unroll
    for (int mt = 0; mt < 4; ++mt)
      av[kt][mt] = *(const bf16x8*)(&sF1[mt * 16 + l15][kt * 32 + l4 * 8]);

  float rs[4][4];
#pragma unroll
  for (int a = 0; a < 4; ++a)
#pragma unroll
    for (int r2 = 0; r2 < 4; ++r2) rs[a][r2] = 0.f;

  const int lwb = chunk * 64 - 64;
  for (int dt = 0; dt < 8; ++dt) {
    const int c0 = dt * 256 + wave * 64;
    f32x4 oacc[4][4];
#pragma unroll
    for (int mt = 0; mt < 4; ++mt)
#pragma unroll
      for (int nt = 0; nt < 4; ++nt) oacc[mt][nt] = fz;
#pragma unroll
    for (int kt = 0; kt < 4; ++kt)
#pragma unroll
      for (int nt = 0; nt < 4; ++nt) {
        const int dv = c0 + nt * 16 + l15;
        int lw = lwb + kt * 32 + l4 * 8;
        if (lw < 0) lw = 0;
        const bf16x8 vv = *(const bf16x8*)(xbT + ((size_t)b * 2048 + dv) * 4096 + lw);
#pragma unroll
        for (int mt = 0; mt < 4; ++mt)
          oacc[mt][nt] = __builtin_amdgcn_mfma_f32_16x16x32_bf16(av[kt][mt], vv, oacc[mt][nt], 0, 0, 0);
      }
#pragma unroll
    for (int mt = 0; mt < 4; ++mt)
#pragma unroll
      for (int r = 0; r < 4; ++r) {
        const int i = mt * 16 + l4 * 4 + r;
#pragma unroll
        for (int nt = 0; nt < 4; ++nt) {
          const float v = oacc[mt][nt][r];
          ob[(size_t)(row0 + i) * 2048 + (c0 + nt * 16 + l15)] = __float2bfloat16(v);
          rs[mt][r] += v * v;
        }
      }
  }

#pragma unroll
  for (int mt = 0; mt < 4; ++mt)
#pragma unroll
    for (int r = 0; r < 4; ++r) {
      float v = rs[mt][r];
      v += __shfl_xor(v, 1); v += __shfl_xor(v, 2);
      v += __shfl_xor(v, 4); v += __shfl_xor(v, 8);
      if (l15 == 0) atomicAdd(&rowsq[mt * 16 + l4 * 4 + r], v);
    }
  __syncthreads();
  if (tid < 64)
    rmsv[row0 + tid] = rsqrtf(rowsq[tid] * (1.f / 2048.f) + 1e-5f);
}

// ---------------------------------------------------------------------------
extern "C" void kernel_launch(void* const* d_in, const int* in_sizes, int n_in,
                              void* d_out, int out_size, void* d_ws, size_t ws_size,
                              hipStream_t stream) {
  const float* x   = (const float*)d_in[0];
  const float* Wq  = (const float*)d_in[1];
  const float* Wk  = (const float*)d_in[2];
  const float* Wog = (const float*)d_in[3];
  const float* Wig = (const float*)d_in[4];
  const float* Wo  = (const float*)d_in[5];
  const float* gnw = (const float*)d_in[6];
  float* out = (float*)d_out;

  char* w = (char*)d_ws;
  auto alloc = [&](size_t bytes) {
    char* p = w;
    w += (bytes + 255) & ~(size_t)255;
    return p;
  };
  bf16*  wqkb   = (bf16*)alloc((size_t)256 * 2048 * 2);
  bf16*  wogb   = (bf16*)alloc((size_t)2048 * 2048 * 2);
  bf16*  wigb   = (bf16*)alloc((size_t)2048 * 2048 * 2);
  bf16*  wob    = (bf16*)alloc((size_t)2048 * 2048 * 2);
  bf16*  xb     = (bf16*)alloc((size_t)8192 * 2048 * 2);
  bf16*  xbT    = (bf16*)alloc((size_t)8192 * 2048 * 2);
  float* logits = (float*)alloc((size_t)8192 * 256 * 4);
  bf16*  qbuf   = (bf16*)alloc((size_t)8192 * 128 * 2);
  bf16*  kbuf   = (bf16*)alloc((size_t)8192 * 128 * 2);
  float* gfbuf  = (float*)alloc((size_t)8192 * 128 * 4);
  bf16*  obuf   = (bf16*)alloc((size_t)8192 * 2048 * 2);
  float* rmsbuf = (float*)alloc((size_t)8192 * 4);
  bf16*  gatedb = xbT;  // xbT dead after gla_kernel -> reuse for gated

  // weights -> bf16
  cvt_bf16_kernel<<<dim3((65536 + 255) / 256), 256, 0, stream>>>(Wq, wqkb, 65536);
  cvt_bf16_kernel<<<dim3((65536 + 255) / 256), 256, 0, stream>>>(Wk, wqkb + 262144, 65536);
  cvt_bf16_kernel<<<dim3((1048576 + 255) / 256), 256, 0, stream>>>(Wog, wogb, 1048576);
  cvt_bf16_kernel<<<dim3((1048576 + 255) / 256), 256, 0, stream>>>(Wig, wigb, 1048576);
  cvt_bf16_kernel<<<dim3((1048576 + 255) / 256), 256, 0, stream>>>(Wo, wob, 1048576);

  // x -> xb + xbT
  convert_x_kernel<<<dim3(64, 32, 2), 256, 0, stream>>>(x, xb, xbT);

  // logits = x @ [Wq;Wk]^T  (small N -> keep 128^2 kernel)
  gemm_bt<0><<<dim3(64, 2), 256, 0, stream>>>(
      xb, wqkb, nullptr, nullptr, logits, nullptr, nullptr, nullptr, nullptr,
      8192, 256, 2048);

  // q/k/gf
  qk_post_kernel<<<dim3(8192), 64, 0, stream>>>(logits, qbuf, kbuf, gfbuf);

  // GLA -> o (bf16) + rms_inv
  gla_kernel<<<dim3(64, 2), 256, 0, stream>>>(qbuf, kbuf, gfbuf, xbT, obuf, rmsbuf);

  // go = o@Wog^T + x@Wig^T ; gated = RMSNorm(o)*g * swish(go)  (fused epilogue)
  gemm256<1><<<dim3(256), 512, 0, stream>>>(
      obuf, wogb, xb, wigb, nullptr, gatedb, obuf, rmsbuf, gnw, 8192, 2048);

  // out = gated @ Wo^T
  gemm256<2><<<dim3(256), 512, 0, stream>>>(
      gatedb, wob, nullptr, nullptr, out, nullptr, nullptr, nullptr, nullptr,
      8192, 2048);

  (void)in_sizes; (void)n_in; (void)out_size; (void)ws_size;
}